// Round 25
// baseline (209.319 us; speedup 1.0000x reference)
//
#include <hip/hip_runtime.h>

#define NN 100000
#define NE 600000
#define NG 64
#define FD 128
#define NB 98   // scan blocks of 1024: 98*1024 >= NN
#define EPAD 1300000  // padded edge capacity: NE + 7*NN
#define GEMM_BLOCKS 512   // 2 blocks/CU (64 KB LDS each), 4 waves/block
#define SRCM 0x1FFFFu

typedef __attribute__((ext_vector_type(8))) short s8v;
typedef __attribute__((ext_vector_type(4))) float f4v;

__device__ inline float bflo(unsigned u) { return __uint_as_float(u << 16); }
__device__ inline float bfhi(unsigned u) { return __uint_as_float(u & 0xFFFF0000u); }
__device__ inline unsigned f2bfbits(float f) {  // round-to-nearest-even
  unsigned x = __float_as_uint(f);
  return (x + 0x7FFFu + ((x >> 16) & 1u)) >> 16;
}
__device__ inline unsigned pack2(float a, float b) { return f2bfbits(a) | (f2bfbits(b) << 16); }

// ---------------- fused prep: degree count + W casts + W3@Wl fold + graph ranges ----------------
__global__ void k_prep(const int* __restrict__ col, int* __restrict__ counts,
                       const float* __restrict__ W1, const float* __restrict__ W2,
                       const float* __restrict__ W3, const float* __restrict__ Wl,
                       const float* __restrict__ b3,
                       unsigned short* __restrict__ WTh, unsigned short* __restrict__ WTl,
                       float* __restrict__ w3wl,   // [FD*2 + 2]
                       const int* __restrict__ batch, int* __restrict__ starts,
                       int* __restrict__ ends) {
  int tid = blockIdx.x * 256 + threadIdx.x;
  if (tid < NE) atomicAdd(&counts[col[tid]], 1);
  if (tid < FD) {   // fold W3 @ Wl -> [FD][2]
    float s0 = 0.f, s1 = 0.f;
    for (int o = 0; o < FD; ++o) {
      float w = W3[tid * FD + o];
      s0 += w * Wl[o * 2];
      s1 += w * Wl[o * 2 + 1];
    }
    w3wl[tid * 2] = s0;
    w3wl[tid * 2 + 1] = s1;
  } else if (tid < FD + 2) {  // fold b3 @ Wl
    int c = tid - FD;
    float s = 0.f;
    for (int o = 0; o < FD; ++o) s += b3[o] * Wl[o * 2 + c];
    w3wl[FD * 2 + c] = s;
  }
  if (tid < 2 * FD * FD) {
    int which = tid / (FD * FD);
    int r = tid - which * (FD * FD);
    const float* W = which == 0 ? W1 : W2;
    int k = r >> 7, n = r & 127;
    float v = W[r];
    unsigned hb = f2bfbits(v);
    float hf = __uint_as_float(hb << 16);
    unsigned lb = f2bfbits(v - hf);
    WTh[which * FD * FD + n * FD + k] = (unsigned short)hb;
    WTl[which * FD * FD + n * FD + k] = (unsigned short)lb;
  }
  int n = tid;
  if (n >= NN) return;
  int g = batch[n];
  if (n == 0) {
    starts[g] = 0;
    for (int q = 0; q < g; ++q) { starts[q] = 0; ends[q] = 0; }
  } else {
    int gp = batch[n - 1];
    if (gp != g) {
      ends[gp] = n;
      starts[g] = n;
      for (int q = gp + 1; q < g; ++q) { starts[q] = n; ends[q] = n; }
    }
  }
  if (n == NN - 1) {
    ends[g] = NN;
    for (int q = g + 1; q < NG; ++q) { starts[q] = NN; ends[q] = NN; }
  }
}

// block sums over PADDED counts (pad to 8) + dinv
__global__ void k_bsum(const int* __restrict__ counts, int* __restrict__ bsum,
                       float* __restrict__ dinv) {
  __shared__ int wsm[16];
  int b = blockIdx.x, t = threadIdx.x;
  int i = b * 1024 + t;
  int c = (i < NN) ? counts[i] : 0;
  if (i < NN) dinv[i] = rsqrtf((float)c + 1.0f);
  int x = (i < NN) ? ((c + 7) & ~7) : 0;
#pragma unroll
  for (int d = 32; d; d >>= 1) x += __shfl_down(x, d);
  if ((t & 63) == 0) wsm[t >> 6] = x;
  __syncthreads();
  if (t < 16) {
    int s = wsm[t];
#pragma unroll
    for (int d = 8; d; d >>= 1) s += __shfl_down(s, d);
    if (t == 0) bsum[b] = s;
  }
}

// scan2 with inlined block-offset reduction + pad-slot zeroing (moved out of
// k_fill: each node thread knows its pad range [end-pad+deg, end) right here;
// removes ~350K random ops from the fill kernel)
__global__ void k_scan2(const int* __restrict__ counts, const int* __restrict__ bsum,
                        int* __restrict__ indptr, uint2* __restrict__ edges) {
  __shared__ int wsm[16];
  __shared__ int s_eb;
  int b = blockIdx.x, t = threadIdx.x;
  int i = b * 1024 + t;
  int lane = t & 63, wid = t >> 6;

  if (wid == 0) {
    int s = 0;
    if (lane < NB && lane < b) s += bsum[lane];
    int l2 = lane + 64;
    if (l2 < NB && l2 < b) s += bsum[l2];
#pragma unroll
    for (int d = 32; d; d >>= 1) s += __shfl_down(s, d);
    if (lane == 0) s_eb = s;
  }

  int cr = (i < NN) ? counts[i] : 0;
  int x = (i < NN) ? ((cr + 7) & ~7) : 0;
  int inc = x;
#pragma unroll
  for (int d = 1; d < 64; d <<= 1) { int y = __shfl_up(inc, d); if (lane >= d) inc += y; }
  if (lane == 63) wsm[wid] = inc;
  __syncthreads();
  if (wid == 0) {
    int s = (lane < 16) ? wsm[lane] : 0;
#pragma unroll
    for (int d = 1; d < 16; d <<= 1) { int y = __shfl_up(s, d); if (lane >= d) s += y; }
    if (lane < 16) wsm[lane] = s;
  }
  __syncthreads();
  int woff = wid ? wsm[wid - 1] : 0;
  if (i < NN) {
    int end = s_eb + woff + inc;
    indptr[i + 1] = end;
    for (int p = end - x + cr; p < end; ++p) edges[p] = make_uint2(0u, 0u);
  }
  if (i == 0) indptr[0] = 0;
}

// edge scatter only (pads zeroed in k_scan2). Record: {src, w}.
__global__ void k_fill(const int* __restrict__ row, const int* __restrict__ col,
                       const int* __restrict__ indptr, int* __restrict__ cursor,
                       const float* __restrict__ dinv, uint2* __restrict__ edges) {
  int tid = blockIdx.x * 256 + threadIdx.x;
  if (tid >= NE) return;
  int c = col[tid], r = row[tid];
  int p = indptr[c] + atomicAdd(&cursor[c], 1);
  edges[p] = make_uint2((unsigned)r, __float_as_uint(dinv[r] * dinv[c]));
}

// ---------------- MFMA GEMM (layers 1,2) ----------------
// 256-thread, uncapped (512-thread caps at 128 VGPR and spills: 3x confirmed).
// f32 layer: 3-DEEP prefetch ring (LDS caps occupancy at 2 blocks/CU, so the
// extra VGPR is free; waves own ~3 tiles -> prologue issues nearly all loads).
// bf16 layers: RT=2 + 2-deep prefetch.
template <int F32A>
__global__ __launch_bounds__(256) void k_gemm(const void* __restrict__ Aab,
                                              const unsigned short* __restrict__ WThi,
                                              const unsigned short* __restrict__ WTlo,
                                              unsigned short* __restrict__ Hb) {
  constexpr int RT = F32A ? 1 : 2;
  constexpr int ROWS = 16 * RT;
  constexpr int NTL = NN / ROWS;
  __shared__ unsigned short wt[256 * 128];
  int t = threadIdx.x, lane = t & 63, w = t >> 6;
  int r16 = lane & 15, kg = lane >> 4;

  {
    const unsigned short* src = (t < 128) ? (WThi + t * FD) : (WTlo + (t - 128) * FD);
#pragma unroll
    for (int j = 0; j < 16; ++j) {
      int ch = j ^ (t & 7);
      *(s8v*)&wt[t * 128 + ch * 8] = *(const s8v*)(src + j * 8);
    }
  }
  __syncthreads();

  const int stride = GEMM_BLOCKS * 4;
  int tile = blockIdx.x * 4 + w;

  float4 aF[8], bF[8], cF[8], dF[8];   // 3-deep ring for f32
  s8v b0B[RT][4], b1B[RT][4], b2B[RT][4];  // 2-deep for bf16

  if (F32A) {
    int l0 = (tile < NTL) ? tile : 0;
    int l1 = (tile + stride < NTL) ? (tile + stride) : l0;
    int l2 = (tile + 2 * stride < NTL) ? (tile + 2 * stride) : l0;
    const float* p0 = (const float*)Aab + (size_t)(l0 * 16 + r16) * FD + kg * 8;
    const float* p1 = (const float*)Aab + (size_t)(l1 * 16 + r16) * FD + kg * 8;
    const float* p2 = (const float*)Aab + (size_t)(l2 * 16 + r16) * FD + kg * 8;
#pragma unroll
    for (int c = 0; c < 4; ++c) {
      aF[c * 2] = *(const float4*)(p0 + c * 32); aF[c * 2 + 1] = *(const float4*)(p0 + c * 32 + 4);
      bF[c * 2] = *(const float4*)(p1 + c * 32); bF[c * 2 + 1] = *(const float4*)(p1 + c * 32 + 4);
      cF[c * 2] = *(const float4*)(p2 + c * 32); cF[c * 2 + 1] = *(const float4*)(p2 + c * 32 + 4);
    }
  } else {
    int l0 = (tile < NTL) ? tile : 0;
    int l1 = (tile + stride < NTL) ? (tile + stride) : l0;
#pragma unroll
    for (int rt = 0; rt < RT; ++rt) {
      const unsigned short* p0 =
          (const unsigned short*)Aab + (size_t)(l0 * ROWS + rt * 16 + r16) * FD + kg * 8;
      const unsigned short* p1 =
          (const unsigned short*)Aab + (size_t)(l1 * ROWS + rt * 16 + r16) * FD + kg * 8;
#pragma unroll
      for (int c = 0; c < 4; ++c) {
        b0B[rt][c] = *(const s8v*)(p0 + c * 32);
        b1B[rt][c] = *(const s8v*)(p1 + c * 32);
      }
    }
  }

  while (tile < NTL) {
    int next = tile + stride;

    {  // issue deepest prefetch
      if (F32A) {
        int nld = (tile + 3 * stride < NTL) ? (tile + 3 * stride) : tile;
        const float* ap = (const float*)Aab + (size_t)(nld * 16 + r16) * FD + kg * 8;
#pragma unroll
        for (int c = 0; c < 4; ++c) {
          dF[c * 2] = *(const float4*)(ap + c * 32);
          dF[c * 2 + 1] = *(const float4*)(ap + c * 32 + 4);
        }
      } else {
        int nld = (tile + 2 * stride < NTL) ? (tile + 2 * stride) : tile;
#pragma unroll
        for (int rt = 0; rt < RT; ++rt) {
          const unsigned short* ap =
              (const unsigned short*)Aab + (size_t)(nld * ROWS + rt * 16 + r16) * FD + kg * 8;
#pragma unroll
          for (int c = 0; c < 4; ++c) b2B[rt][c] = *(const s8v*)(ap + c * 32);
        }
      }
    }

    s8v afr[RT][4];
    if (F32A) {
#pragma unroll
      for (int c = 0; c < 4; ++c) {
        float4 p0 = aF[c * 2], p1 = aF[c * 2 + 1];
        s8v f;
        f[0] = (short)f2bfbits(p0.x); f[1] = (short)f2bfbits(p0.y);
        f[2] = (short)f2bfbits(p0.z); f[3] = (short)f2bfbits(p0.w);
        f[4] = (short)f2bfbits(p1.x); f[5] = (short)f2bfbits(p1.y);
        f[6] = (short)f2bfbits(p1.z); f[7] = (short)f2bfbits(p1.w);
        afr[0][c] = f;
      }
    } else {
#pragma unroll
      for (int rt = 0; rt < RT; ++rt)
#pragma unroll
        for (int c = 0; c < 4; ++c) afr[rt][c] = b0B[rt][c];
    }

    f4v acc[RT][8];
#pragma unroll
    for (int rt = 0; rt < RT; ++rt)
#pragma unroll
      for (int n = 0; n < 8; ++n) acc[rt][n] = (f4v){0.f, 0.f, 0.f, 0.f};

#pragma unroll
    for (int n = 0; n < 8; ++n) {
      s8v bh[4], bl[4];
#pragma unroll
      for (int c = 0; c < 4; ++c) {
        int ch = (c * 4 + kg) ^ (r16 & 7);
        bh[c] = *(const s8v*)&wt[(n * 16 + r16) * 128 + ch * 8];
        bl[c] = *(const s8v*)&wt[(128 + n * 16 + r16) * 128 + ch * 8];
      }
#pragma unroll
      for (int c = 0; c < 4; ++c)
#pragma unroll
        for (int rt = 0; rt < RT; ++rt)
          acc[rt][n] = __builtin_amdgcn_mfma_f32_16x16x32_bf16(bh[c], afr[rt][c], acc[rt][n], 0, 0, 0);
#pragma unroll
      for (int c = 0; c < 4; ++c)
#pragma unroll
        for (int rt = 0; rt < RT; ++rt)
          acc[rt][n] = __builtin_amdgcn_mfma_f32_16x16x32_bf16(bl[c], afr[rt][c], acc[rt][n], 0, 0, 0);
    }

#pragma unroll
    for (int rt = 0; rt < RT; ++rt) {
      int node = tile * ROWS + rt * 16 + r16;
      unsigned short* hp = Hb + (size_t)node * FD + kg * 4;
#pragma unroll
      for (int n = 0; n < 8; ++n) {
        uint2 v = make_uint2(pack2(acc[rt][n][0], acc[rt][n][1]),
                             pack2(acc[rt][n][2], acc[rt][n][3]));
        *(uint2*)(hp + n * 16) = v;
      }
    }

    // rotate rings
    if (F32A) {
#pragma unroll
      for (int c = 0; c < 8; ++c) { aF[c] = bF[c]; bF[c] = cF[c]; cF[c] = dF[c]; }
    } else {
#pragma unroll
      for (int rt = 0; rt < RT; ++rt)
#pragma unroll
        for (int c = 0; c < 4; ++c) { b0B[rt][c] = b1B[rt][c]; b1B[rt][c] = b2B[rt][c]; }
    }
    tile = next;
  }
}

// ---------------- aggregation: 4 nodes/wave, uint4 lanes, 8-deep ----------------
__global__ __launch_bounds__(256) void k_agg(const uint4* __restrict__ H4,
                                             const int* __restrict__ indptr,
                                             const uint4* __restrict__ edges2,
                                             const float* __restrict__ dinv,
                                             const float* __restrict__ bias,
                                             uint4* __restrict__ out4, int relu) {
  int wid = (blockIdx.x * 256 + threadIdx.x) >> 6;
  int ql = threadIdx.x & 15;
  int n = wid * 4 + ((threadIdx.x >> 4) & 3);
  if (n >= NN) return;
  float dv = dinv[n];
  float s2 = dv * dv;
  uint4 u = H4[(size_t)n * 16 + ql];
  float a0 = s2 * bflo(u.x), a1 = s2 * bfhi(u.x);
  float a2 = s2 * bflo(u.y), a3 = s2 * bfhi(u.y);
  float a4 = s2 * bflo(u.z), a5 = s2 * bfhi(u.z);
  float a6 = s2 * bflo(u.w), a7 = s2 * bfhi(u.w);
  int e0 = indptr[n] >> 1, e1 = indptr[n + 1] >> 1;
  for (int e = e0; e < e1; e += 4) {
    uint4 E0 = edges2[e], E1 = edges2[e + 1], E2 = edges2[e + 2], E3 = edges2[e + 3];
    uint4 v0 = H4[(size_t)(E0.x & SRCM) * 16 + ql];
    uint4 v1 = H4[(size_t)(E0.z & SRCM) * 16 + ql];
    uint4 v2 = H4[(size_t)(E1.x & SRCM) * 16 + ql];
    uint4 v3 = H4[(size_t)(E1.z & SRCM) * 16 + ql];
    uint4 v4 = H4[(size_t)(E2.x & SRCM) * 16 + ql];
    uint4 v5 = H4[(size_t)(E2.z & SRCM) * 16 + ql];
    uint4 v6 = H4[(size_t)(E3.x & SRCM) * 16 + ql];
    uint4 v7 = H4[(size_t)(E3.z & SRCM) * 16 + ql];
    float w0 = __uint_as_float(E0.y), w1 = __uint_as_float(E0.w);
    float w2 = __uint_as_float(E1.y), w3 = __uint_as_float(E1.w);
    float w4 = __uint_as_float(E2.y), w5 = __uint_as_float(E2.w);
    float w6 = __uint_as_float(E3.y), w7 = __uint_as_float(E3.w);
    a0 += w0 * bflo(v0.x); a1 += w0 * bfhi(v0.x); a2 += w0 * bflo(v0.y); a3 += w0 * bfhi(v0.y);
    a4 += w0 * bflo(v0.z); a5 += w0 * bfhi(v0.z); a6 += w0 * bflo(v0.w); a7 += w0 * bfhi(v0.w);
    a0 += w1 * bflo(v1.x); a1 += w1 * bfhi(v1.x); a2 += w1 * bflo(v1.y); a3 += w1 * bfhi(v1.y);
    a4 += w1 * bflo(v1.z); a5 += w1 * bfhi(v1.z); a6 += w1 * bflo(v1.w); a7 += w1 * bfhi(v1.w);
    a0 += w2 * bflo(v2.x); a1 += w2 * bfhi(v2.x); a2 += w2 * bflo(v2.y); a3 += w2 * bfhi(v2.y);
    a4 += w2 * bflo(v2.z); a5 += w2 * bfhi(v2.z); a6 += w2 * bflo(v2.w); a7 += w2 * bfhi(v2.w);
    a0 += w3 * bflo(v3.x); a1 += w3 * bfhi(v3.x); a2 += w3 * bflo(v3.y); a3 += w3 * bfhi(v3.y);
    a4 += w3 * bflo(v3.z); a5 += w3 * bfhi(v3.z); a6 += w3 * bflo(v3.w); a7 += w3 * bfhi(v3.w);
    a0 += w4 * bflo(v4.x); a1 += w4 * bfhi(v4.x); a2 += w4 * bflo(v4.y); a3 += w4 * bfhi(v4.y);
    a4 += w4 * bflo(v4.z); a5 += w4 * bfhi(v4.z); a6 += w4 * bflo(v4.w); a7 += w4 * bfhi(v4.w);
    a0 += w5 * bflo(v5.x); a1 += w5 * bfhi(v5.x); a2 += w5 * bflo(v5.y); a3 += w5 * bfhi(v5.y);
    a4 += w5 * bflo(v5.z); a5 += w5 * bfhi(v5.z); a6 += w5 * bflo(v5.w); a7 += w5 * bfhi(v5.w);
    a0 += w6 * bflo(v6.x); a1 += w6 * bfhi(v6.x); a2 += w6 * bflo(v6.y); a3 += w6 * bfhi(v6.y);
    a4 += w6 * bflo(v6.z); a5 += w6 * bfhi(v6.z); a6 += w6 * bflo(v6.w); a7 += w6 * bfhi(v6.w);
    a0 += w7 * bflo(v7.x); a1 += w7 * bfhi(v7.x); a2 += w7 * bflo(v7.y); a3 += w7 * bfhi(v7.y);
    a4 += w7 * bflo(v7.z); a5 += w7 * bfhi(v7.z); a6 += w7 * bflo(v7.w); a7 += w7 * bfhi(v7.w);
  }
  a0 += bias[ql * 8];     a1 += bias[ql * 8 + 1];
  a2 += bias[ql * 8 + 2]; a3 += bias[ql * 8 + 3];
  a4 += bias[ql * 8 + 4]; a5 += bias[ql * 8 + 5];
  a6 += bias[ql * 8 + 6]; a7 += bias[ql * 8 + 7];
  if (relu) {
    a0 = fmaxf(a0, 0.f); a1 = fmaxf(a1, 0.f); a2 = fmaxf(a2, 0.f); a3 = fmaxf(a3, 0.f);
    a4 = fmaxf(a4, 0.f); a5 = fmaxf(a5, 0.f); a6 = fmaxf(a6, 0.f); a7 = fmaxf(a7, 0.f);
  }
  out4[(size_t)n * 16 + ql] =
      make_uint4(pack2(a0, a1), pack2(a2, a3), pack2(a4, a5), pack2(a6, a7));
}

// ---------------- Z accumulate, ATOMIC-FREE: grid = 64 graphs x 8 slices ----------------
__global__ __launch_bounds__(256) void k_zacc(const uint4* __restrict__ H4,
                                              const uint4* __restrict__ edges2,
                                              const int* __restrict__ indptr,
                                              const float* __restrict__ dinv,
                                              const int* __restrict__ starts,
                                              const int* __restrict__ ends,
                                              float* __restrict__ Zpart) {
  __shared__ float zred[16][FD];
  int g = blockIdx.x >> 3, s = blockIdx.x & 7;
  int q = threadIdx.x >> 4, ql = threadIdx.x & 15;
  int qg = s * 16 + q;

  float a0 = 0.f, a1 = 0.f, a2 = 0.f, a3 = 0.f, a4 = 0.f, a5 = 0.f, a6 = 0.f, a7 = 0.f;

  int n0 = starts[g], n1 = ends[g];

  for (int n = n0 + qg; n < n1; n += 128) {
    float dv = dinv[n];
    float wq = dv * dv;
    uint4 v = H4[(size_t)n * 16 + ql];
    a0 += wq * bflo(v.x); a1 += wq * bfhi(v.x);
    a2 += wq * bflo(v.y); a3 += wq * bfhi(v.y);
    a4 += wq * bflo(v.z); a5 += wq * bfhi(v.z);
    a6 += wq * bflo(v.w); a7 += wq * bfhi(v.w);
  }

  int p0 = indptr[n0] >> 1, p1 = indptr[n1] >> 1;
  int ngroups = (p1 - p0) >> 2;
  for (int gi = qg; gi < ngroups; gi += 128) {
    int e = p0 + gi * 4;
    uint4 E0 = edges2[e], E1 = edges2[e + 1], E2 = edges2[e + 2], E3 = edges2[e + 3];
    uint4 v0 = H4[(size_t)(E0.x & SRCM) * 16 + ql];
    uint4 v1 = H4[(size_t)(E0.z & SRCM) * 16 + ql];
    uint4 v2 = H4[(size_t)(E1.x & SRCM) * 16 + ql];
    uint4 v3 = H4[(size_t)(E1.z & SRCM) * 16 + ql];
    uint4 v4 = H4[(size_t)(E2.x & SRCM) * 16 + ql];
    uint4 v5 = H4[(size_t)(E2.z & SRCM) * 16 + ql];
    uint4 v6 = H4[(size_t)(E3.x & SRCM) * 16 + ql];
    uint4 v7 = H4[(size_t)(E3.z & SRCM) * 16 + ql];
    float w0 = __uint_as_float(E0.y), w1 = __uint_as_float(E0.w);
    float w2 = __uint_as_float(E1.y), w3 = __uint_as_float(E1.w);
    float w4 = __uint_as_float(E2.y), w5 = __uint_as_float(E2.w);
    float w6 = __uint_as_float(E3.y), w7 = __uint_as_float(E3.w);
    a0 += w0 * bflo(v0.x); a1 += w0 * bfhi(v0.x); a2 += w0 * bflo(v0.y); a3 += w0 * bfhi(v0.y);
    a4 += w0 * bflo(v0.z); a5 += w0 * bfhi(v0.z); a6 += w0 * bflo(v0.w); a7 += w0 * bfhi(v0.w);
    a0 += w1 * bflo(v1.x); a1 += w1 * bfhi(v1.x); a2 += w1 * bflo(v1.y); a3 += w1 * bfhi(v1.y);
    a4 += w1 * bflo(v1.z); a5 += w1 * bfhi(v1.z); a6 += w1 * bflo(v1.w); a7 += w1 * bfhi(v1.w);
    a0 += w2 * bflo(v2.x); a1 += w2 * bfhi(v2.x); a2 += w2 * bflo(v2.y); a3 += w2 * bfhi(v2.y);
    a4 += w2 * bflo(v2.z); a5 += w2 * bfhi(v2.z); a6 += w2 * bflo(v2.w); a7 += w2 * bfhi(v2.w);
    a0 += w3 * bflo(v3.x); a1 += w3 * bfhi(v3.x); a2 += w3 * bflo(v3.y); a3 += w3 * bfhi(v3.y);
    a4 += w3 * bflo(v3.z); a5 += w3 * bfhi(v3.z); a6 += w3 * bflo(v3.w); a7 += w3 * bfhi(v3.w);
    a0 += w4 * bflo(v4.x); a1 += w4 * bfhi(v4.x); a2 += w4 * bflo(v4.y); a3 += w4 * bfhi(v4.y);
    a4 += w4 * bflo(v4.z); a5 += w4 * bfhi(v4.z); a6 += w4 * bflo(v4.w); a7 += w4 * bfhi(v4.w);
    a0 += w5 * bflo(v5.x); a1 += w5 * bfhi(v5.x); a2 += w5 * bflo(v5.y); a3 += w5 * bfhi(v5.y);
    a4 += w5 * bflo(v5.z); a5 += w5 * bfhi(v5.z); a6 += w5 * bflo(v5.w); a7 += w5 * bfhi(v5.w);
    a0 += w6 * bflo(v6.x); a1 += w6 * bfhi(v6.x); a2 += w6 * bflo(v6.y); a3 += w6 * bfhi(v6.y);
    a4 += w6 * bflo(v6.z); a5 += w6 * bfhi(v6.z); a6 += w6 * bflo(v6.w); a7 += w6 * bfhi(v6.w);
    a0 += w7 * bflo(v7.x); a1 += w7 * bfhi(v7.x); a2 += w7 * bflo(v7.y); a3 += w7 * bfhi(v7.y);
    a4 += w7 * bflo(v7.z); a5 += w7 * bfhi(v7.z); a6 += w7 * bflo(v7.w); a7 += w7 * bfhi(v7.w);
  }

  float* zq = &zred[q][ql * 8];
  zq[0] = a0; zq[1] = a1; zq[2] = a2; zq[3] = a3;
  zq[4] = a4; zq[5] = a5; zq[6] = a6; zq[7] = a7;
  __syncthreads();
  int t = threadIdx.x;
  if (t < FD) {
    float sum = 0.f;
#pragma unroll
    for (int qq = 0; qq < 16; ++qq) sum += zred[qq][t];
    Zpart[(size_t)(g * 8 + s) * FD + t] = sum;
  }
}

// ---------------- head3: one block per graph ----------------
__global__ void k_head3(const float* __restrict__ Zpart, const int* __restrict__ starts,
                        const int* __restrict__ ends, const float* __restrict__ w3wl,
                        const float* __restrict__ bl, float* __restrict__ out) {
  __shared__ float wpart[2][2];
  int g = blockIdx.x;
  int t = threadIdx.x;  // 128
  float zsum = 0.f;
#pragma unroll
  for (int s = 0; s < 8; ++s) zsum += Zpart[(size_t)(g * 8 + s) * FD + t];
  float a0 = zsum * w3wl[t * 2];
  float a1 = zsum * w3wl[t * 2 + 1];
#pragma unroll
  for (int d = 32; d; d >>= 1) {
    a0 += __shfl_down(a0, d);
    a1 += __shfl_down(a1, d);
  }
  int lane = t & 63, wv = t >> 6;
  if (lane == 0) { wpart[wv][0] = a0; wpart[wv][1] = a1; }
  __syncthreads();
  if (t == 0) {
    int cnt = ends[g] - starts[g];
    if (cnt < 0) cnt = 0;
    float inv = 1.f / (float)(cnt > 0 ? cnt : 1);
    float s0 = (wpart[0][0] + wpart[1][0]) * inv + (cnt > 0 ? w3wl[FD * 2] : 0.f) + bl[0];
    float s1 = (wpart[0][1] + wpart[1][1]) * inv + (cnt > 0 ? w3wl[FD * 2 + 1] : 0.f) + bl[1];
    out[g * 2] = s0;
    out[g * 2 + 1] = s1;
  }
}

// ---------------- host ----------------

extern "C" void kernel_launch(void* const* d_in, const int* in_sizes, int n_in,
                              void* d_out, int out_size, void* d_ws, size_t ws_size,
                              hipStream_t stream) {
  const float* x  = (const float*)d_in[0];
  const int* ei   = (const int*)d_in[1];
  const int* bat  = (const int*)d_in[2];
  const float* W1 = (const float*)d_in[3];
  const float* b1 = (const float*)d_in[4];
  const float* W2 = (const float*)d_in[5];
  const float* b2 = (const float*)d_in[6];
  const float* W3 = (const float*)d_in[7];
  const float* b3 = (const float*)d_in[8];
  const float* Wl = (const float*)d_in[9];
  const float* bl = (const float*)d_in[10];
  float* out = (float*)d_out;

  char* ws = (char*)d_ws;
  size_t off = 0;
  auto alloc = [&](size_t bytes) {
    void* p = ws + off;
    off += (bytes + 255) & ~(size_t)255;
    return p;
  };
  int* counts  = (int*)alloc(NN * 4);
  int* cursor  = (int*)alloc(NN * 4);
  int* indptr  = (int*)alloc((NN + 1) * 4);
  float* dinv  = (float*)alloc(NN * 4);
  int* bsum    = (int*)alloc(NB * 4);
  int* starts  = (int*)alloc(NG * 4);
  int* ends    = (int*)alloc(NG * 4);
  float* Zpart = (float*)alloc(NG * 8 * FD * 4);
  float* w3wl  = (float*)alloc((FD * 2 + 2) * 4);
  uint2* edges = (uint2*)alloc((size_t)EPAD * 8);
  unsigned short* Hb   = (unsigned short*)alloc((size_t)NN * FD * 2);
  unsigned short* Abuf = (unsigned short*)alloc((size_t)NN * FD * 2);
  unsigned short* WTh  = (unsigned short*)alloc(2 * FD * FD * 2);
  unsigned short* WTl  = (unsigned short*)alloc(2 * FD * FD * 2);

  const int* row = ei;
  const int* col = ei + NE;

  hipMemsetAsync(counts, 0, (size_t)((char*)cursor - (char*)counts) + NN * 4, stream);
  k_prep<<<(NE + 255) / 256, 256, 0, stream>>>(col, counts, W1, W2, W3, Wl, b3,
                                               WTh, WTl, w3wl, bat, starts, ends);
  k_bsum<<<NB, 1024, 0, stream>>>(counts, bsum, dinv);
  k_scan2<<<NB, 1024, 0, stream>>>(counts, bsum, indptr, edges);
  k_fill<<<(NE + 255) / 256, 256, 0, stream>>>(row, col, indptr, cursor, dinv, edges);

  int aggGrid = (NN + 15) / 16;

  k_gemm<1><<<GEMM_BLOCKS, 256, 0, stream>>>(x, WTh, WTl, Hb);
  k_agg<<<aggGrid, 256, 0, stream>>>((const uint4*)Hb, indptr, (const uint4*)edges, dinv, b1,
                                     (uint4*)Abuf, 1);
  k_gemm<0><<<GEMM_BLOCKS, 256, 0, stream>>>(Abuf, WTh + FD * FD, WTl + FD * FD, Hb);
  k_agg<<<aggGrid, 256, 0, stream>>>((const uint4*)Hb, indptr, (const uint4*)edges, dinv, b2,
                                     (uint4*)Abuf, 1);
  k_zacc<<<NG * 8, 256, 0, stream>>>((const uint4*)Abuf, (const uint4*)edges, indptr, dinv,
                                     starts, ends, Zpart);
  k_head3<<<NG, 128, 0, stream>>>(Zpart, starts, ends, w3wl, bl, out);
}

// Round 26
// 207.949 us; speedup vs baseline: 1.0066x; 1.0066x over previous
//
#include <hip/hip_runtime.h>

#define NN 100000
#define NE 600000
#define NG 64
#define FD 128
#define NB 98   // scan blocks of 1024: 98*1024 >= NN
#define EPAD 1300000  // padded edge capacity: NE + 7*NN
#define GEMM_BLOCKS 512   // 2 blocks/CU (64 KB LDS each), 4 waves/block
#define SRCM 0x1FFFFu

typedef __attribute__((ext_vector_type(8))) short s8v;
typedef __attribute__((ext_vector_type(4))) float f4v;

__device__ inline float bflo(unsigned u) { return __uint_as_float(u << 16); }
__device__ inline float bfhi(unsigned u) { return __uint_as_float(u & 0xFFFF0000u); }
__device__ inline unsigned f2bfbits(float f) {  // round-to-nearest-even
  unsigned x = __float_as_uint(f);
  return (x + 0x7FFFu + ((x >> 16) & 1u)) >> 16;
}
__device__ inline unsigned pack2(float a, float b) { return f2bfbits(a) | (f2bfbits(b) << 16); }

// ---------------- fused prep: degree count + W casts + W3@Wl fold + graph ranges ----------------
__global__ void k_prep(const int* __restrict__ col, int* __restrict__ counts,
                       const float* __restrict__ W1, const float* __restrict__ W2,
                       const float* __restrict__ W3, const float* __restrict__ Wl,
                       const float* __restrict__ b3,
                       unsigned short* __restrict__ WTh, unsigned short* __restrict__ WTl,
                       float* __restrict__ w3wl,   // [FD*2 + 2]
                       const int* __restrict__ batch, int* __restrict__ starts,
                       int* __restrict__ ends) {
  int tid = blockIdx.x * 256 + threadIdx.x;
  if (tid < NE) atomicAdd(&counts[col[tid]], 1);
  if (tid < FD) {   // fold W3 @ Wl -> [FD][2]
    float s0 = 0.f, s1 = 0.f;
    for (int o = 0; o < FD; ++o) {
      float w = W3[tid * FD + o];
      s0 += w * Wl[o * 2];
      s1 += w * Wl[o * 2 + 1];
    }
    w3wl[tid * 2] = s0;
    w3wl[tid * 2 + 1] = s1;
  } else if (tid < FD + 2) {  // fold b3 @ Wl
    int c = tid - FD;
    float s = 0.f;
    for (int o = 0; o < FD; ++o) s += b3[o] * Wl[o * 2 + c];
    w3wl[FD * 2 + c] = s;
  }
  if (tid < 2 * FD * FD) {
    int which = tid / (FD * FD);
    int r = tid - which * (FD * FD);
    const float* W = which == 0 ? W1 : W2;
    int k = r >> 7, n = r & 127;
    float v = W[r];
    unsigned hb = f2bfbits(v);
    float hf = __uint_as_float(hb << 16);
    unsigned lb = f2bfbits(v - hf);
    WTh[which * FD * FD + n * FD + k] = (unsigned short)hb;
    WTl[which * FD * FD + n * FD + k] = (unsigned short)lb;
  }
  int n = tid;
  if (n >= NN) return;
  int g = batch[n];
  if (n == 0) {
    starts[g] = 0;
    for (int q = 0; q < g; ++q) { starts[q] = 0; ends[q] = 0; }
  } else {
    int gp = batch[n - 1];
    if (gp != g) {
      ends[gp] = n;
      starts[g] = n;
      for (int q = gp + 1; q < g; ++q) { starts[q] = n; ends[q] = n; }
    }
  }
  if (n == NN - 1) {
    ends[g] = NN;
    for (int q = g + 1; q < NG; ++q) { starts[q] = NN; ends[q] = NN; }
  }
}

// block sums over PADDED counts (pad to 8) + dinv
__global__ void k_bsum(const int* __restrict__ counts, int* __restrict__ bsum,
                       float* __restrict__ dinv) {
  __shared__ int wsm[16];
  int b = blockIdx.x, t = threadIdx.x;
  int i = b * 1024 + t;
  int c = (i < NN) ? counts[i] : 0;
  if (i < NN) dinv[i] = rsqrtf((float)c + 1.0f);
  int x = (i < NN) ? ((c + 7) & ~7) : 0;
#pragma unroll
  for (int d = 32; d; d >>= 1) x += __shfl_down(x, d);
  if ((t & 63) == 0) wsm[t >> 6] = x;
  __syncthreads();
  if (t < 16) {
    int s = wsm[t];
#pragma unroll
    for (int d = 8; d; d >>= 1) s += __shfl_down(s, d);
    if (t == 0) bsum[b] = s;
  }
}

// scan2 with inlined block-offset reduction + pad-slot zeroing
__global__ void k_scan2(const int* __restrict__ counts, const int* __restrict__ bsum,
                        int* __restrict__ indptr, uint2* __restrict__ edges) {
  __shared__ int wsm[16];
  __shared__ int s_eb;
  int b = blockIdx.x, t = threadIdx.x;
  int i = b * 1024 + t;
  int lane = t & 63, wid = t >> 6;

  if (wid == 0) {
    int s = 0;
    if (lane < NB && lane < b) s += bsum[lane];
    int l2 = lane + 64;
    if (l2 < NB && l2 < b) s += bsum[l2];
#pragma unroll
    for (int d = 32; d; d >>= 1) s += __shfl_down(s, d);
    if (lane == 0) s_eb = s;
  }

  int cr = (i < NN) ? counts[i] : 0;
  int x = (i < NN) ? ((cr + 7) & ~7) : 0;
  int inc = x;
#pragma unroll
  for (int d = 1; d < 64; d <<= 1) { int y = __shfl_up(inc, d); if (lane >= d) inc += y; }
  if (lane == 63) wsm[wid] = inc;
  __syncthreads();
  if (wid == 0) {
    int s = (lane < 16) ? wsm[lane] : 0;
#pragma unroll
    for (int d = 1; d < 16; d <<= 1) { int y = __shfl_up(s, d); if (lane >= d) s += y; }
    if (lane < 16) wsm[lane] = s;
  }
  __syncthreads();
  int woff = wid ? wsm[wid - 1] : 0;
  if (i < NN) {
    int end = s_eb + woff + inc;
    indptr[i + 1] = end;
    for (int p = end - x + cr; p < end; ++p) edges[p] = make_uint2(0u, 0u);
  }
  if (i == 0) indptr[0] = 0;
}

// edge scatter only (pads zeroed in k_scan2). Record: {src, w}.
__global__ void k_fill(const int* __restrict__ row, const int* __restrict__ col,
                       const int* __restrict__ indptr, int* __restrict__ cursor,
                       const float* __restrict__ dinv, uint2* __restrict__ edges) {
  int tid = blockIdx.x * 256 + threadIdx.x;
  if (tid >= NE) return;
  int c = col[tid], r = row[tid];
  int p = indptr[c] + atomicAdd(&cursor[c], 1);
  edges[p] = make_uint2((unsigned)r, __float_as_uint(dinv[r] * dinv[c]));
}

// ---------------- MFMA GEMM (layers 1,2): R24 champion form ----------------
// 256-thread, uncapped. f32: 2-deep prefetch ring; bf16: RT=2 + 1-deep.
// (R25's deeper rings cost ~6 us of pure register-rotation tax — reverted.)
template <int F32A>
__global__ __launch_bounds__(256) void k_gemm(const void* __restrict__ Aab,
                                              const unsigned short* __restrict__ WThi,
                                              const unsigned short* __restrict__ WTlo,
                                              unsigned short* __restrict__ Hb) {
  constexpr int RT = F32A ? 1 : 2;
  constexpr int ROWS = 16 * RT;
  constexpr int NTL = NN / ROWS;
  __shared__ unsigned short wt[256 * 128];
  int t = threadIdx.x, lane = t & 63, w = t >> 6;
  int r16 = lane & 15, kg = lane >> 4;

  {
    const unsigned short* src = (t < 128) ? (WThi + t * FD) : (WTlo + (t - 128) * FD);
#pragma unroll
    for (int j = 0; j < 16; ++j) {
      int ch = j ^ (t & 7);
      *(s8v*)&wt[t * 128 + ch * 8] = *(const s8v*)(src + j * 8);
    }
  }
  __syncthreads();

  const int stride = GEMM_BLOCKS * 4;
  int tile = blockIdx.x * 4 + w;

  float4 aF[8], bF[8], cF[8];
  s8v curB[RT][4], nxtB[RT][4];

  if (F32A) {
    int ld0 = (tile < NTL) ? tile : 0;
    const float* ap = (const float*)Aab + (size_t)(ld0 * 16 + r16) * FD + kg * 8;
#pragma unroll
    for (int c = 0; c < 4; ++c) {
      aF[c * 2] = *(const float4*)(ap + c * 32);
      aF[c * 2 + 1] = *(const float4*)(ap + c * 32 + 4);
    }
    int ld1 = (tile + stride < NTL) ? (tile + stride) : ld0;
    const float* ap1 = (const float*)Aab + (size_t)(ld1 * 16 + r16) * FD + kg * 8;
#pragma unroll
    for (int c = 0; c < 4; ++c) {
      bF[c * 2] = *(const float4*)(ap1 + c * 32);
      bF[c * 2 + 1] = *(const float4*)(ap1 + c * 32 + 4);
    }
  } else {
    if (tile < NTL) {
#pragma unroll
      for (int rt = 0; rt < RT; ++rt) {
        const unsigned short* ap =
            (const unsigned short*)Aab + (size_t)(tile * ROWS + rt * 16 + r16) * FD + kg * 8;
#pragma unroll
        for (int c = 0; c < 4; ++c) curB[rt][c] = *(const s8v*)(ap + c * 32);
      }
    }
  }

  while (tile < NTL) {
    int next = tile + stride;

    {
      if (F32A) {
        int nld = (tile + 2 * stride < NTL) ? (tile + 2 * stride) : tile;
        const float* ap = (const float*)Aab + (size_t)(nld * 16 + r16) * FD + kg * 8;
#pragma unroll
        for (int c = 0; c < 4; ++c) {
          cF[c * 2] = *(const float4*)(ap + c * 32);
          cF[c * 2 + 1] = *(const float4*)(ap + c * 32 + 4);
        }
      } else {
        int nld = (next < NTL) ? next : tile;
#pragma unroll
        for (int rt = 0; rt < RT; ++rt) {
          const unsigned short* ap =
              (const unsigned short*)Aab + (size_t)(nld * ROWS + rt * 16 + r16) * FD + kg * 8;
#pragma unroll
          for (int c = 0; c < 4; ++c) nxtB[rt][c] = *(const s8v*)(ap + c * 32);
        }
      }
    }

    s8v afr[RT][4];
    if (F32A) {
#pragma unroll
      for (int c = 0; c < 4; ++c) {
        float4 p0 = aF[c * 2], p1 = aF[c * 2 + 1];
        s8v f;
        f[0] = (short)f2bfbits(p0.x); f[1] = (short)f2bfbits(p0.y);
        f[2] = (short)f2bfbits(p0.z); f[3] = (short)f2bfbits(p0.w);
        f[4] = (short)f2bfbits(p1.x); f[5] = (short)f2bfbits(p1.y);
        f[6] = (short)f2bfbits(p1.z); f[7] = (short)f2bfbits(p1.w);
        afr[0][c] = f;
      }
    } else {
#pragma unroll
      for (int rt = 0; rt < RT; ++rt)
#pragma unroll
        for (int c = 0; c < 4; ++c) afr[rt][c] = curB[rt][c];
    }

    f4v acc[RT][8];
#pragma unroll
    for (int rt = 0; rt < RT; ++rt)
#pragma unroll
      for (int n = 0; n < 8; ++n) acc[rt][n] = (f4v){0.f, 0.f, 0.f, 0.f};

#pragma unroll
    for (int n = 0; n < 8; ++n) {
      s8v bh[4], bl[4];
#pragma unroll
      for (int c = 0; c < 4; ++c) {
        int ch = (c * 4 + kg) ^ (r16 & 7);
        bh[c] = *(const s8v*)&wt[(n * 16 + r16) * 128 + ch * 8];
        bl[c] = *(const s8v*)&wt[(128 + n * 16 + r16) * 128 + ch * 8];
      }
#pragma unroll
      for (int c = 0; c < 4; ++c)
#pragma unroll
        for (int rt = 0; rt < RT; ++rt)
          acc[rt][n] = __builtin_amdgcn_mfma_f32_16x16x32_bf16(bh[c], afr[rt][c], acc[rt][n], 0, 0, 0);
#pragma unroll
      for (int c = 0; c < 4; ++c)
#pragma unroll
        for (int rt = 0; rt < RT; ++rt)
          acc[rt][n] = __builtin_amdgcn_mfma_f32_16x16x32_bf16(bl[c], afr[rt][c], acc[rt][n], 0, 0, 0);
    }

#pragma unroll
    for (int rt = 0; rt < RT; ++rt) {
      int node = tile * ROWS + rt * 16 + r16;
      unsigned short* hp = Hb + (size_t)node * FD + kg * 4;
#pragma unroll
      for (int n = 0; n < 8; ++n) {
        uint2 v = make_uint2(pack2(acc[rt][n][0], acc[rt][n][1]),
                             pack2(acc[rt][n][2], acc[rt][n][3]));
        *(uint2*)(hp + n * 16) = v;
      }
    }

    if (F32A) {
#pragma unroll
      for (int c = 0; c < 8; ++c) { aF[c] = bF[c]; bF[c] = cF[c]; }
    } else {
#pragma unroll
      for (int rt = 0; rt < RT; ++rt)
#pragma unroll
        for (int c = 0; c < 4; ++c) curB[rt][c] = nxtB[rt][c];
    }
    tile = next;
  }
}

// ---------------- aggregation: 4 nodes/wave, uint4 lanes, 8-deep ----------------
__global__ __launch_bounds__(256) void k_agg(const uint4* __restrict__ H4,
                                             const int* __restrict__ indptr,
                                             const uint4* __restrict__ edges2,
                                             const float* __restrict__ dinv,
                                             const float* __restrict__ bias,
                                             uint4* __restrict__ out4, int relu) {
  int wid = (blockIdx.x * 256 + threadIdx.x) >> 6;
  int ql = threadIdx.x & 15;
  int n = wid * 4 + ((threadIdx.x >> 4) & 3);
  if (n >= NN) return;
  float dv = dinv[n];
  float s2 = dv * dv;
  uint4 u = H4[(size_t)n * 16 + ql];
  float a0 = s2 * bflo(u.x), a1 = s2 * bfhi(u.x);
  float a2 = s2 * bflo(u.y), a3 = s2 * bfhi(u.y);
  float a4 = s2 * bflo(u.z), a5 = s2 * bfhi(u.z);
  float a6 = s2 * bflo(u.w), a7 = s2 * bfhi(u.w);
  int e0 = indptr[n] >> 1, e1 = indptr[n + 1] >> 1;
  for (int e = e0; e < e1; e += 4) {
    uint4 E0 = edges2[e], E1 = edges2[e + 1], E2 = edges2[e + 2], E3 = edges2[e + 3];
    uint4 v0 = H4[(size_t)(E0.x & SRCM) * 16 + ql];
    uint4 v1 = H4[(size_t)(E0.z & SRCM) * 16 + ql];
    uint4 v2 = H4[(size_t)(E1.x & SRCM) * 16 + ql];
    uint4 v3 = H4[(size_t)(E1.z & SRCM) * 16 + ql];
    uint4 v4 = H4[(size_t)(E2.x & SRCM) * 16 + ql];
    uint4 v5 = H4[(size_t)(E2.z & SRCM) * 16 + ql];
    uint4 v6 = H4[(size_t)(E3.x & SRCM) * 16 + ql];
    uint4 v7 = H4[(size_t)(E3.z & SRCM) * 16 + ql];
    float w0 = __uint_as_float(E0.y), w1 = __uint_as_float(E0.w);
    float w2 = __uint_as_float(E1.y), w3 = __uint_as_float(E1.w);
    float w4 = __uint_as_float(E2.y), w5 = __uint_as_float(E2.w);
    float w6 = __uint_as_float(E3.y), w7 = __uint_as_float(E3.w);
    a0 += w0 * bflo(v0.x); a1 += w0 * bfhi(v0.x); a2 += w0 * bflo(v0.y); a3 += w0 * bfhi(v0.y);
    a4 += w0 * bflo(v0.z); a5 += w0 * bfhi(v0.z); a6 += w0 * bflo(v0.w); a7 += w0 * bfhi(v0.w);
    a0 += w1 * bflo(v1.x); a1 += w1 * bfhi(v1.x); a2 += w1 * bflo(v1.y); a3 += w1 * bfhi(v1.y);
    a4 += w1 * bflo(v1.z); a5 += w1 * bfhi(v1.z); a6 += w1 * bflo(v1.w); a7 += w1 * bfhi(v1.w);
    a0 += w2 * bflo(v2.x); a1 += w2 * bfhi(v2.x); a2 += w2 * bflo(v2.y); a3 += w2 * bfhi(v2.y);
    a4 += w2 * bflo(v2.z); a5 += w2 * bfhi(v2.z); a6 += w2 * bflo(v2.w); a7 += w2 * bfhi(v2.w);
    a0 += w3 * bflo(v3.x); a1 += w3 * bfhi(v3.x); a2 += w3 * bflo(v3.y); a3 += w3 * bfhi(v3.y);
    a4 += w3 * bflo(v3.z); a5 += w3 * bfhi(v3.z); a6 += w3 * bflo(v3.w); a7 += w3 * bfhi(v3.w);
    a0 += w4 * bflo(v4.x); a1 += w4 * bfhi(v4.x); a2 += w4 * bflo(v4.y); a3 += w4 * bfhi(v4.y);
    a4 += w4 * bflo(v4.z); a5 += w4 * bfhi(v4.z); a6 += w4 * bflo(v4.w); a7 += w4 * bfhi(v4.w);
    a0 += w5 * bflo(v5.x); a1 += w5 * bfhi(v5.x); a2 += w5 * bflo(v5.y); a3 += w5 * bfhi(v5.y);
    a4 += w5 * bflo(v5.z); a5 += w5 * bfhi(v5.z); a6 += w5 * bflo(v5.w); a7 += w5 * bfhi(v5.w);
    a0 += w6 * bflo(v6.x); a1 += w6 * bfhi(v6.x); a2 += w6 * bflo(v6.y); a3 += w6 * bfhi(v6.y);
    a4 += w6 * bflo(v6.z); a5 += w6 * bfhi(v6.z); a6 += w6 * bflo(v6.w); a7 += w6 * bfhi(v6.w);
    a0 += w7 * bflo(v7.x); a1 += w7 * bfhi(v7.x); a2 += w7 * bflo(v7.y); a3 += w7 * bfhi(v7.y);
    a4 += w7 * bflo(v7.z); a5 += w7 * bfhi(v7.z); a6 += w7 * bflo(v7.w); a7 += w7 * bfhi(v7.w);
  }
  a0 += bias[ql * 8];     a1 += bias[ql * 8 + 1];
  a2 += bias[ql * 8 + 2]; a3 += bias[ql * 8 + 3];
  a4 += bias[ql * 8 + 4]; a5 += bias[ql * 8 + 5];
  a6 += bias[ql * 8 + 6]; a7 += bias[ql * 8 + 7];
  if (relu) {
    a0 = fmaxf(a0, 0.f); a1 = fmaxf(a1, 0.f); a2 = fmaxf(a2, 0.f); a3 = fmaxf(a3, 0.f);
    a4 = fmaxf(a4, 0.f); a5 = fmaxf(a5, 0.f); a6 = fmaxf(a6, 0.f); a7 = fmaxf(a7, 0.f);
  }
  out4[(size_t)n * 16 + ql] =
      make_uint4(pack2(a0, a1), pack2(a2, a3), pack2(a4, a5), pack2(a6, a7));
}

// ---------------- Z accumulate, ATOMIC-FREE: grid = 64 graphs x 8 slices ----------------
__global__ __launch_bounds__(256) void k_zacc(const uint4* __restrict__ H4,
                                              const uint4* __restrict__ edges2,
                                              const int* __restrict__ indptr,
                                              const float* __restrict__ dinv,
                                              const int* __restrict__ starts,
                                              const int* __restrict__ ends,
                                              float* __restrict__ Zpart) {
  __shared__ float zred[16][FD];
  int g = blockIdx.x >> 3, s = blockIdx.x & 7;
  int q = threadIdx.x >> 4, ql = threadIdx.x & 15;
  int qg = s * 16 + q;

  float a0 = 0.f, a1 = 0.f, a2 = 0.f, a3 = 0.f, a4 = 0.f, a5 = 0.f, a6 = 0.f, a7 = 0.f;

  int n0 = starts[g], n1 = ends[g];

  for (int n = n0 + qg; n < n1; n += 128) {
    float dv = dinv[n];
    float wq = dv * dv;
    uint4 v = H4[(size_t)n * 16 + ql];
    a0 += wq * bflo(v.x); a1 += wq * bfhi(v.x);
    a2 += wq * bflo(v.y); a3 += wq * bfhi(v.y);
    a4 += wq * bflo(v.z); a5 += wq * bfhi(v.z);
    a6 += wq * bflo(v.w); a7 += wq * bfhi(v.w);
  }

  int p0 = indptr[n0] >> 1, p1 = indptr[n1] >> 1;
  int ngroups = (p1 - p0) >> 2;
  for (int gi = qg; gi < ngroups; gi += 128) {
    int e = p0 + gi * 4;
    uint4 E0 = edges2[e], E1 = edges2[e + 1], E2 = edges2[e + 2], E3 = edges2[e + 3];
    uint4 v0 = H4[(size_t)(E0.x & SRCM) * 16 + ql];
    uint4 v1 = H4[(size_t)(E0.z & SRCM) * 16 + ql];
    uint4 v2 = H4[(size_t)(E1.x & SRCM) * 16 + ql];
    uint4 v3 = H4[(size_t)(E1.z & SRCM) * 16 + ql];
    uint4 v4 = H4[(size_t)(E2.x & SRCM) * 16 + ql];
    uint4 v5 = H4[(size_t)(E2.z & SRCM) * 16 + ql];
    uint4 v6 = H4[(size_t)(E3.x & SRCM) * 16 + ql];
    uint4 v7 = H4[(size_t)(E3.z & SRCM) * 16 + ql];
    float w0 = __uint_as_float(E0.y), w1 = __uint_as_float(E0.w);
    float w2 = __uint_as_float(E1.y), w3 = __uint_as_float(E1.w);
    float w4 = __uint_as_float(E2.y), w5 = __uint_as_float(E2.w);
    float w6 = __uint_as_float(E3.y), w7 = __uint_as_float(E3.w);
    a0 += w0 * bflo(v0.x); a1 += w0 * bfhi(v0.x); a2 += w0 * bflo(v0.y); a3 += w0 * bfhi(v0.y);
    a4 += w0 * bflo(v0.z); a5 += w0 * bfhi(v0.z); a6 += w0 * bflo(v0.w); a7 += w0 * bfhi(v0.w);
    a0 += w1 * bflo(v1.x); a1 += w1 * bfhi(v1.x); a2 += w1 * bflo(v1.y); a3 += w1 * bfhi(v1.y);
    a4 += w1 * bflo(v1.z); a5 += w1 * bfhi(v1.z); a6 += w1 * bflo(v1.w); a7 += w1 * bfhi(v1.w);
    a0 += w2 * bflo(v2.x); a1 += w2 * bfhi(v2.x); a2 += w2 * bflo(v2.y); a3 += w2 * bfhi(v2.y);
    a4 += w2 * bflo(v2.z); a5 += w2 * bfhi(v2.z); a6 += w2 * bflo(v2.w); a7 += w2 * bfhi(v2.w);
    a0 += w3 * bflo(v3.x); a1 += w3 * bfhi(v3.x); a2 += w3 * bflo(v3.y); a3 += w3 * bfhi(v3.y);
    a4 += w3 * bflo(v3.z); a5 += w3 * bfhi(v3.z); a6 += w3 * bflo(v3.w); a7 += w3 * bfhi(v3.w);
    a0 += w4 * bflo(v4.x); a1 += w4 * bfhi(v4.x); a2 += w4 * bflo(v4.y); a3 += w4 * bfhi(v4.y);
    a4 += w4 * bflo(v4.z); a5 += w4 * bfhi(v4.z); a6 += w4 * bflo(v4.w); a7 += w4 * bfhi(v4.w);
    a0 += w5 * bflo(v5.x); a1 += w5 * bfhi(v5.x); a2 += w5 * bflo(v5.y); a3 += w5 * bfhi(v5.y);
    a4 += w5 * bflo(v5.z); a5 += w5 * bfhi(v5.z); a6 += w5 * bflo(v5.w); a7 += w5 * bfhi(v5.w);
    a0 += w6 * bflo(v6.x); a1 += w6 * bfhi(v6.x); a2 += w6 * bflo(v6.y); a3 += w6 * bfhi(v6.y);
    a4 += w6 * bflo(v6.z); a5 += w6 * bfhi(v6.z); a6 += w6 * bflo(v6.w); a7 += w6 * bfhi(v6.w);
    a0 += w7 * bflo(v7.x); a1 += w7 * bfhi(v7.x); a2 += w7 * bflo(v7.y); a3 += w7 * bfhi(v7.y);
    a4 += w7 * bflo(v7.z); a5 += w7 * bfhi(v7.z); a6 += w7 * bflo(v7.w); a7 += w7 * bfhi(v7.w);
  }

  float* zq = &zred[q][ql * 8];
  zq[0] = a0; zq[1] = a1; zq[2] = a2; zq[3] = a3;
  zq[4] = a4; zq[5] = a5; zq[6] = a6; zq[7] = a7;
  __syncthreads();
  int t = threadIdx.x;
  if (t < FD) {
    float sum = 0.f;
#pragma unroll
    for (int qq = 0; qq < 16; ++qq) sum += zred[qq][t];
    Zpart[(size_t)(g * 8 + s) * FD + t] = sum;
  }
}

// ---------------- head3: one block per graph ----------------
__global__ void k_head3(const float* __restrict__ Zpart, const int* __restrict__ starts,
                        const int* __restrict__ ends, const float* __restrict__ w3wl,
                        const float* __restrict__ bl, float* __restrict__ out) {
  __shared__ float wpart[2][2];
  int g = blockIdx.x;
  int t = threadIdx.x;  // 128
  float zsum = 0.f;
#pragma unroll
  for (int s = 0; s < 8; ++s) zsum += Zpart[(size_t)(g * 8 + s) * FD + t];
  float a0 = zsum * w3wl[t * 2];
  float a1 = zsum * w3wl[t * 2 + 1];
#pragma unroll
  for (int d = 32; d; d >>= 1) {
    a0 += __shfl_down(a0, d);
    a1 += __shfl_down(a1, d);
  }
  int lane = t & 63, wv = t >> 6;
  if (lane == 0) { wpart[wv][0] = a0; wpart[wv][1] = a1; }
  __syncthreads();
  if (t == 0) {
    int cnt = ends[g] - starts[g];
    if (cnt < 0) cnt = 0;
    float inv = 1.f / (float)(cnt > 0 ? cnt : 1);
    float s0 = (wpart[0][0] + wpart[1][0]) * inv + (cnt > 0 ? w3wl[FD * 2] : 0.f) + bl[0];
    float s1 = (wpart[0][1] + wpart[1][1]) * inv + (cnt > 0 ? w3wl[FD * 2 + 1] : 0.f) + bl[1];
    out[g * 2] = s0;
    out[g * 2 + 1] = s1;
  }
}

// ---------------- host ----------------

extern "C" void kernel_launch(void* const* d_in, const int* in_sizes, int n_in,
                              void* d_out, int out_size, void* d_ws, size_t ws_size,
                              hipStream_t stream) {
  const float* x  = (const float*)d_in[0];
  const int* ei   = (const int*)d_in[1];
  const int* bat  = (const int*)d_in[2];
  const float* W1 = (const float*)d_in[3];
  const float* b1 = (const float*)d_in[4];
  const float* W2 = (const float*)d_in[5];
  const float* b2 = (const float*)d_in[6];
  const float* W3 = (const float*)d_in[7];
  const float* b3 = (const float*)d_in[8];
  const float* Wl = (const float*)d_in[9];
  const float* bl = (const float*)d_in[10];
  float* out = (float*)d_out;

  char* ws = (char*)d_ws;
  size_t off = 0;
  auto alloc = [&](size_t bytes) {
    void* p = ws + off;
    off += (bytes + 255) & ~(size_t)255;
    return p;
  };
  int* counts  = (int*)alloc(NN * 4);
  int* cursor  = (int*)alloc(NN * 4);
  int* indptr  = (int*)alloc((NN + 1) * 4);
  float* dinv  = (float*)alloc(NN * 4);
  int* bsum    = (int*)alloc(NB * 4);
  int* starts  = (int*)alloc(NG * 4);
  int* ends    = (int*)alloc(NG * 4);
  float* Zpart = (float*)alloc(NG * 8 * FD * 4);
  float* w3wl  = (float*)alloc((FD * 2 + 2) * 4);
  uint2* edges = (uint2*)alloc((size_t)EPAD * 8);
  unsigned short* Hb   = (unsigned short*)alloc((size_t)NN * FD * 2);
  unsigned short* Abuf = (unsigned short*)alloc((size_t)NN * FD * 2);
  unsigned short* WTh  = (unsigned short*)alloc(2 * FD * FD * 2);
  unsigned short* WTl  = (unsigned short*)alloc(2 * FD * FD * 2);

  const int* row = ei;
  const int* col = ei + NE;

  hipMemsetAsync(counts, 0, (size_t)((char*)cursor - (char*)counts) + NN * 4, stream);
  k_prep<<<(NE + 255) / 256, 256, 0, stream>>>(col, counts, W1, W2, W3, Wl, b3,
                                               WTh, WTl, w3wl, bat, starts, ends);
  k_bsum<<<NB, 1024, 0, stream>>>(counts, bsum, dinv);
  k_scan2<<<NB, 1024, 0, stream>>>(counts, bsum, indptr, edges);
  k_fill<<<(NE + 255) / 256, 256, 0, stream>>>(row, col, indptr, cursor, dinv, edges);

  int aggGrid = (NN + 15) / 16;

  k_gemm<1><<<GEMM_BLOCKS, 256, 0, stream>>>(x, WTh, WTl, Hb);
  k_agg<<<aggGrid, 256, 0, stream>>>((const uint4*)Hb, indptr, (const uint4*)edges, dinv, b1,
                                     (uint4*)Abuf, 1);
  k_gemm<0><<<GEMM_BLOCKS, 256, 0, stream>>>(Abuf, WTh + FD * FD, WTl + FD * FD, Hb);
  k_agg<<<aggGrid, 256, 0, stream>>>((const uint4*)Hb, indptr, (const uint4*)edges, dinv, b2,
                                     (uint4*)Abuf, 1);
  k_zacc<<<NG * 8, 256, 0, stream>>>((const uint4*)Abuf, (const uint4*)edges, indptr, dinv,
                                     starts, ends, Zpart);
  k_head3<<<NG, 128, 0, stream>>>(Zpart, starts, ends, w3wl, bl, out);
}

// Round 27
// 202.787 us; speedup vs baseline: 1.0322x; 1.0255x over previous
//
#include <hip/hip_runtime.h>

#define NN 100000
#define NE 600000
#define NG 64
#define FD 128
#define NB 98   // scan blocks of 1024: 98*1024 >= NN
#define EPAD 1300000  // padded edge capacity: NE + 7*NN
#define GEMM_BLOCKS 512   // 2 blocks/CU (64 KB LDS each), 4 waves/block
#define SRCM 0x1FFFFu

typedef __attribute__((ext_vector_type(8))) short s8v;
typedef __attribute__((ext_vector_type(4))) float f4v;

__device__ inline float bflo(unsigned u) { return __uint_as_float(u << 16); }
__device__ inline float bfhi(unsigned u) { return __uint_as_float(u & 0xFFFF0000u); }
__device__ inline unsigned f2bfbits(float f) {  // round-to-nearest-even
  unsigned x = __float_as_uint(f);
  return (x + 0x7FFFu + ((x >> 16) & 1u)) >> 16;
}
__device__ inline unsigned pack2(float a, float b) { return f2bfbits(a) | (f2bfbits(b) << 16); }

// ---------------- fused prep: degree count + W casts + W3@Wl fold + graph ranges ----------------
__global__ void k_prep(const int* __restrict__ col, int* __restrict__ counts,
                       const float* __restrict__ W1, const float* __restrict__ W2,
                       const float* __restrict__ W3, const float* __restrict__ Wl,
                       const float* __restrict__ b3,
                       unsigned short* __restrict__ WTh, unsigned short* __restrict__ WTl,
                       float* __restrict__ w3wl,   // [FD*2 + 2]
                       const int* __restrict__ batch, int* __restrict__ starts,
                       int* __restrict__ ends) {
  int tid = blockIdx.x * 256 + threadIdx.x;
  if (tid < NE) atomicAdd(&counts[col[tid]], 1);
  if (tid < FD) {   // fold W3 @ Wl -> [FD][2]
    float s0 = 0.f, s1 = 0.f;
    for (int o = 0; o < FD; ++o) {
      float w = W3[tid * FD + o];
      s0 += w * Wl[o * 2];
      s1 += w * Wl[o * 2 + 1];
    }
    w3wl[tid * 2] = s0;
    w3wl[tid * 2 + 1] = s1;
  } else if (tid < FD + 2) {  // fold b3 @ Wl
    int c = tid - FD;
    float s = 0.f;
    for (int o = 0; o < FD; ++o) s += b3[o] * Wl[o * 2 + c];
    w3wl[FD * 2 + c] = s;
  }
  if (tid < 2 * FD * FD) {
    int which = tid / (FD * FD);
    int r = tid - which * (FD * FD);
    const float* W = which == 0 ? W1 : W2;
    int k = r >> 7, n = r & 127;
    float v = W[r];
    unsigned hb = f2bfbits(v);
    float hf = __uint_as_float(hb << 16);
    unsigned lb = f2bfbits(v - hf);
    WTh[which * FD * FD + n * FD + k] = (unsigned short)hb;
    WTl[which * FD * FD + n * FD + k] = (unsigned short)lb;
  }
  int n = tid;
  if (n >= NN) return;
  int g = batch[n];
  if (n == 0) {
    starts[g] = 0;
    for (int q = 0; q < g; ++q) { starts[q] = 0; ends[q] = 0; }
  } else {
    int gp = batch[n - 1];
    if (gp != g) {
      ends[gp] = n;
      starts[g] = n;
      for (int q = gp + 1; q < g; ++q) { starts[q] = n; ends[q] = n; }
    }
  }
  if (n == NN - 1) {
    ends[g] = NN;
    for (int q = g + 1; q < NG; ++q) { starts[q] = NN; ends[q] = NN; }
  }
}

// block sums over PADDED counts (pad to 8) + dinv
__global__ void k_bsum(const int* __restrict__ counts, int* __restrict__ bsum,
                       float* __restrict__ dinv) {
  __shared__ int wsm[16];
  int b = blockIdx.x, t = threadIdx.x;
  int i = b * 1024 + t;
  int c = (i < NN) ? counts[i] : 0;
  if (i < NN) dinv[i] = rsqrtf((float)c + 1.0f);
  int x = (i < NN) ? ((c + 7) & ~7) : 0;
#pragma unroll
  for (int d = 32; d; d >>= 1) x += __shfl_down(x, d);
  if ((t & 63) == 0) wsm[t >> 6] = x;
  __syncthreads();
  if (t < 16) {
    int s = wsm[t];
#pragma unroll
    for (int d = 8; d; d >>= 1) s += __shfl_down(s, d);
    if (t == 0) bsum[b] = s;
  }
}

// scan2 with inlined block-offset reduction
__global__ void k_scan2(const int* __restrict__ counts, const int* __restrict__ bsum,
                        int* __restrict__ indptr) {
  __shared__ int wsm[16];
  __shared__ int s_eb;
  int b = blockIdx.x, t = threadIdx.x;
  int i = b * 1024 + t;
  int lane = t & 63, wid = t >> 6;

  if (wid == 0) {
    int s = 0;
    if (lane < NB && lane < b) s += bsum[lane];
    int l2 = lane + 64;
    if (l2 < NB && l2 < b) s += bsum[l2];
#pragma unroll
    for (int d = 32; d; d >>= 1) s += __shfl_down(s, d);
    if (lane == 0) s_eb = s;
  }

  int x = (i < NN) ? ((counts[i] + 7) & ~7) : 0;
  int inc = x;
#pragma unroll
  for (int d = 1; d < 64; d <<= 1) { int y = __shfl_up(inc, d); if (lane >= d) inc += y; }
  if (lane == 63) wsm[wid] = inc;
  __syncthreads();
  if (wid == 0) {
    int s = (lane < 16) ? wsm[lane] : 0;
#pragma unroll
    for (int d = 1; d < 16; d <<= 1) { int y = __shfl_up(s, d); if (lane >= d) s += y; }
    if (lane < 16) wsm[lane] = s;
  }
  __syncthreads();
  int woff = wid ? wsm[wid - 1] : 0;
  if (i < NN) indptr[i + 1] = s_eb + woff + inc;
  if (i == 0) indptr[0] = 0;
}

// edge scatter + pad-slot zeroing (R24 champion form). Pad slots
// [indptr[n]+deg(n), indptr[n+1]) are disjoint from cursor-scattered real
// edges -> race-free; pad records {0, 0.0f} are exact no-ops.
__global__ void k_fill(const int* __restrict__ row, const int* __restrict__ col,
                       const int* __restrict__ indptr, int* __restrict__ cursor,
                       const int* __restrict__ counts,
                       const float* __restrict__ dinv, uint2* __restrict__ edges) {
  int tid = blockIdx.x * 256 + threadIdx.x;
  if (tid < NN) {
    int base = indptr[tid] + counts[tid];
    int end = indptr[tid + 1];
    for (int p = base; p < end; ++p) edges[p] = make_uint2(0u, 0u);
  }
  if (tid >= NE) return;
  int c = col[tid], r = row[tid];
  int p = indptr[c] + atomicAdd(&cursor[c], 1);
  edges[p] = make_uint2((unsigned)r, __float_as_uint(dinv[r] * dinv[c]));
}

// ---------------- MFMA GEMM (layers 1,2): R24 champion form ----------------
// 256-thread, uncapped (512-thread caps at 128 VGPR and spills: 3x confirmed).
// f32: 2-deep prefetch ring; bf16: RT=2 + 1-deep. Deeper rings cost pure
// register-rotation tax (R25 evidence).
template <int F32A>
__global__ __launch_bounds__(256) void k_gemm(const void* __restrict__ Aab,
                                              const unsigned short* __restrict__ WThi,
                                              const unsigned short* __restrict__ WTlo,
                                              unsigned short* __restrict__ Hb) {
  constexpr int RT = F32A ? 1 : 2;
  constexpr int ROWS = 16 * RT;
  constexpr int NTL = NN / ROWS;
  __shared__ unsigned short wt[256 * 128];
  int t = threadIdx.x, lane = t & 63, w = t >> 6;
  int r16 = lane & 15, kg = lane >> 4;

  {
    const unsigned short* src = (t < 128) ? (WThi + t * FD) : (WTlo + (t - 128) * FD);
#pragma unroll
    for (int j = 0; j < 16; ++j) {
      int ch = j ^ (t & 7);
      *(s8v*)&wt[t * 128 + ch * 8] = *(const s8v*)(src + j * 8);
    }
  }
  __syncthreads();

  const int stride = GEMM_BLOCKS * 4;
  int tile = blockIdx.x * 4 + w;

  float4 aF[8], bF[8], cF[8];
  s8v curB[RT][4], nxtB[RT][4];

  if (F32A) {
    int ld0 = (tile < NTL) ? tile : 0;
    const float* ap = (const float*)Aab + (size_t)(ld0 * 16 + r16) * FD + kg * 8;
#pragma unroll
    for (int c = 0; c < 4; ++c) {
      aF[c * 2] = *(const float4*)(ap + c * 32);
      aF[c * 2 + 1] = *(const float4*)(ap + c * 32 + 4);
    }
    int ld1 = (tile + stride < NTL) ? (tile + stride) : ld0;
    const float* ap1 = (const float*)Aab + (size_t)(ld1 * 16 + r16) * FD + kg * 8;
#pragma unroll
    for (int c = 0; c < 4; ++c) {
      bF[c * 2] = *(const float4*)(ap1 + c * 32);
      bF[c * 2 + 1] = *(const float4*)(ap1 + c * 32 + 4);
    }
  } else {
    if (tile < NTL) {
#pragma unroll
      for (int rt = 0; rt < RT; ++rt) {
        const unsigned short* ap =
            (const unsigned short*)Aab + (size_t)(tile * ROWS + rt * 16 + r16) * FD + kg * 8;
#pragma unroll
        for (int c = 0; c < 4; ++c) curB[rt][c] = *(const s8v*)(ap + c * 32);
      }
    }
  }

  while (tile < NTL) {
    int next = tile + stride;

    {
      if (F32A) {
        int nld = (tile + 2 * stride < NTL) ? (tile + 2 * stride) : tile;
        const float* ap = (const float*)Aab + (size_t)(nld * 16 + r16) * FD + kg * 8;
#pragma unroll
        for (int c = 0; c < 4; ++c) {
          cF[c * 2] = *(const float4*)(ap + c * 32);
          cF[c * 2 + 1] = *(const float4*)(ap + c * 32 + 4);
        }
      } else {
        int nld = (next < NTL) ? next : tile;
#pragma unroll
        for (int rt = 0; rt < RT; ++rt) {
          const unsigned short* ap =
              (const unsigned short*)Aab + (size_t)(nld * ROWS + rt * 16 + r16) * FD + kg * 8;
#pragma unroll
          for (int c = 0; c < 4; ++c) nxtB[rt][c] = *(const s8v*)(ap + c * 32);
        }
      }
    }

    s8v afr[RT][4];
    if (F32A) {
#pragma unroll
      for (int c = 0; c < 4; ++c) {
        float4 p0 = aF[c * 2], p1 = aF[c * 2 + 1];
        s8v f;
        f[0] = (short)f2bfbits(p0.x); f[1] = (short)f2bfbits(p0.y);
        f[2] = (short)f2bfbits(p0.z); f[3] = (short)f2bfbits(p0.w);
        f[4] = (short)f2bfbits(p1.x); f[5] = (short)f2bfbits(p1.y);
        f[6] = (short)f2bfbits(p1.z); f[7] = (short)f2bfbits(p1.w);
        afr[0][c] = f;
      }
    } else {
#pragma unroll
      for (int rt = 0; rt < RT; ++rt)
#pragma unroll
        for (int c = 0; c < 4; ++c) afr[rt][c] = curB[rt][c];
    }

    f4v acc[RT][8];
#pragma unroll
    for (int rt = 0; rt < RT; ++rt)
#pragma unroll
      for (int n = 0; n < 8; ++n) acc[rt][n] = (f4v){0.f, 0.f, 0.f, 0.f};

#pragma unroll
    for (int n = 0; n < 8; ++n) {
      s8v bh[4], bl[4];
#pragma unroll
      for (int c = 0; c < 4; ++c) {
        int ch = (c * 4 + kg) ^ (r16 & 7);
        bh[c] = *(const s8v*)&wt[(n * 16 + r16) * 128 + ch * 8];
        bl[c] = *(const s8v*)&wt[(128 + n * 16 + r16) * 128 + ch * 8];
      }
#pragma unroll
      for (int c = 0; c < 4; ++c)
#pragma unroll
        for (int rt = 0; rt < RT; ++rt)
          acc[rt][n] = __builtin_amdgcn_mfma_f32_16x16x32_bf16(bh[c], afr[rt][c], acc[rt][n], 0, 0, 0);
#pragma unroll
      for (int c = 0; c < 4; ++c)
#pragma unroll
        for (int rt = 0; rt < RT; ++rt)
          acc[rt][n] = __builtin_amdgcn_mfma_f32_16x16x32_bf16(bl[c], afr[rt][c], acc[rt][n], 0, 0, 0);
    }

#pragma unroll
    for (int rt = 0; rt < RT; ++rt) {
      int node = tile * ROWS + rt * 16 + r16;
      unsigned short* hp = Hb + (size_t)node * FD + kg * 4;
#pragma unroll
      for (int n = 0; n < 8; ++n) {
        uint2 v = make_uint2(pack2(acc[rt][n][0], acc[rt][n][1]),
                             pack2(acc[rt][n][2], acc[rt][n][3]));
        *(uint2*)(hp + n * 16) = v;
      }
    }

    if (F32A) {
#pragma unroll
      for (int c = 0; c < 8; ++c) { aF[c] = bF[c]; bF[c] = cF[c]; }
    } else {
#pragma unroll
      for (int rt = 0; rt < RT; ++rt)
#pragma unroll
        for (int c = 0; c < 4; ++c) curB[rt][c] = nxtB[rt][c];
    }
    tile = next;
  }
}

// ---------------- aggregation: 4 nodes/wave, uint4 lanes, 8-deep ----------------
__global__ __launch_bounds__(256) void k_agg(const uint4* __restrict__ H4,
                                             const int* __restrict__ indptr,
                                             const uint4* __restrict__ edges2,
                                             const float* __restrict__ dinv,
                                             const float* __restrict__ bias,
                                             uint4* __restrict__ out4, int relu) {
  int wid = (blockIdx.x * 256 + threadIdx.x) >> 6;
  int ql = threadIdx.x & 15;
  int n = wid * 4 + ((threadIdx.x >> 4) & 3);
  if (n >= NN) return;
  float dv = dinv[n];
  float s2 = dv * dv;
  uint4 u = H4[(size_t)n * 16 + ql];
  float a0 = s2 * bflo(u.x), a1 = s2 * bfhi(u.x);
  float a2 = s2 * bflo(u.y), a3 = s2 * bfhi(u.y);
  float a4 = s2 * bflo(u.z), a5 = s2 * bfhi(u.z);
  float a6 = s2 * bflo(u.w), a7 = s2 * bfhi(u.w);
  int e0 = indptr[n] >> 1, e1 = indptr[n + 1] >> 1;
  for (int e = e0; e < e1; e += 4) {
    uint4 E0 = edges2[e], E1 = edges2[e + 1], E2 = edges2[e + 2], E3 = edges2[e + 3];
    uint4 v0 = H4[(size_t)(E0.x & SRCM) * 16 + ql];
    uint4 v1 = H4[(size_t)(E0.z & SRCM) * 16 + ql];
    uint4 v2 = H4[(size_t)(E1.x & SRCM) * 16 + ql];
    uint4 v3 = H4[(size_t)(E1.z & SRCM) * 16 + ql];
    uint4 v4 = H4[(size_t)(E2.x & SRCM) * 16 + ql];
    uint4 v5 = H4[(size_t)(E2.z & SRCM) * 16 + ql];
    uint4 v6 = H4[(size_t)(E3.x & SRCM) * 16 + ql];
    uint4 v7 = H4[(size_t)(E3.z & SRCM) * 16 + ql];
    float w0 = __uint_as_float(E0.y), w1 = __uint_as_float(E0.w);
    float w2 = __uint_as_float(E1.y), w3 = __uint_as_float(E1.w);
    float w4 = __uint_as_float(E2.y), w5 = __uint_as_float(E2.w);
    float w6 = __uint_as_float(E3.y), w7 = __uint_as_float(E3.w);
    a0 += w0 * bflo(v0.x); a1 += w0 * bfhi(v0.x); a2 += w0 * bflo(v0.y); a3 += w0 * bfhi(v0.y);
    a4 += w0 * bflo(v0.z); a5 += w0 * bfhi(v0.z); a6 += w0 * bflo(v0.w); a7 += w0 * bfhi(v0.w);
    a0 += w1 * bflo(v1.x); a1 += w1 * bfhi(v1.x); a2 += w1 * bflo(v1.y); a3 += w1 * bfhi(v1.y);
    a4 += w1 * bflo(v1.z); a5 += w1 * bfhi(v1.z); a6 += w1 * bflo(v1.w); a7 += w1 * bfhi(v1.w);
    a0 += w2 * bflo(v2.x); a1 += w2 * bfhi(v2.x); a2 += w2 * bflo(v2.y); a3 += w2 * bfhi(v2.y);
    a4 += w2 * bflo(v2.z); a5 += w2 * bfhi(v2.z); a6 += w2 * bflo(v2.w); a7 += w2 * bfhi(v2.w);
    a0 += w3 * bflo(v3.x); a1 += w3 * bfhi(v3.x); a2 += w3 * bflo(v3.y); a3 += w3 * bfhi(v3.y);
    a4 += w3 * bflo(v3.z); a5 += w3 * bfhi(v3.z); a6 += w3 * bflo(v3.w); a7 += w3 * bfhi(v3.w);
    a0 += w4 * bflo(v4.x); a1 += w4 * bfhi(v4.x); a2 += w4 * bflo(v4.y); a3 += w4 * bfhi(v4.y);
    a4 += w4 * bflo(v4.z); a5 += w4 * bfhi(v4.z); a6 += w4 * bflo(v4.w); a7 += w4 * bfhi(v4.w);
    a0 += w5 * bflo(v5.x); a1 += w5 * bfhi(v5.x); a2 += w5 * bflo(v5.y); a3 += w5 * bfhi(v5.y);
    a4 += w5 * bflo(v5.z); a5 += w5 * bfhi(v5.z); a6 += w5 * bflo(v5.w); a7 += w5 * bfhi(v5.w);
    a0 += w6 * bflo(v6.x); a1 += w6 * bfhi(v6.x); a2 += w6 * bflo(v6.y); a3 += w6 * bfhi(v6.y);
    a4 += w6 * bflo(v6.z); a5 += w6 * bfhi(v6.z); a6 += w6 * bflo(v6.w); a7 += w6 * bfhi(v6.w);
    a0 += w7 * bflo(v7.x); a1 += w7 * bfhi(v7.x); a2 += w7 * bflo(v7.y); a3 += w7 * bfhi(v7.y);
    a4 += w7 * bflo(v7.z); a5 += w7 * bfhi(v7.z); a6 += w7 * bflo(v7.w); a7 += w7 * bfhi(v7.w);
  }
  a0 += bias[ql * 8];     a1 += bias[ql * 8 + 1];
  a2 += bias[ql * 8 + 2]; a3 += bias[ql * 8 + 3];
  a4 += bias[ql * 8 + 4]; a5 += bias[ql * 8 + 5];
  a6 += bias[ql * 8 + 6]; a7 += bias[ql * 8 + 7];
  if (relu) {
    a0 = fmaxf(a0, 0.f); a1 = fmaxf(a1, 0.f); a2 = fmaxf(a2, 0.f); a3 = fmaxf(a3, 0.f);
    a4 = fmaxf(a4, 0.f); a5 = fmaxf(a5, 0.f); a6 = fmaxf(a6, 0.f); a7 = fmaxf(a7, 0.f);
  }
  out4[(size_t)n * 16 + ql] =
      make_uint4(pack2(a0, a1), pack2(a2, a3), pack2(a4, a5), pack2(a6, a7));
}

// ---------------- Z accumulate, ATOMIC-FREE: grid = 64 graphs x 8 slices ----------------
__global__ __launch_bounds__(256) void k_zacc(const uint4* __restrict__ H4,
                                              const uint4* __restrict__ edges2,
                                              const int* __restrict__ indptr,
                                              const float* __restrict__ dinv,
                                              const int* __restrict__ starts,
                                              const int* __restrict__ ends,
                                              float* __restrict__ Zpart) {
  __shared__ float zred[16][FD];
  int g = blockIdx.x >> 3, s = blockIdx.x & 7;
  int q = threadIdx.x >> 4, ql = threadIdx.x & 15;
  int qg = s * 16 + q;

  float a0 = 0.f, a1 = 0.f, a2 = 0.f, a3 = 0.f, a4 = 0.f, a5 = 0.f, a6 = 0.f, a7 = 0.f;

  int n0 = starts[g], n1 = ends[g];

  for (int n = n0 + qg; n < n1; n += 128) {
    float dv = dinv[n];
    float wq = dv * dv;
    uint4 v = H4[(size_t)n * 16 + ql];
    a0 += wq * bflo(v.x); a1 += wq * bfhi(v.x);
    a2 += wq * bflo(v.y); a3 += wq * bfhi(v.y);
    a4 += wq * bflo(v.z); a5 += wq * bfhi(v.z);
    a6 += wq * bflo(v.w); a7 += wq * bfhi(v.w);
  }

  int p0 = indptr[n0] >> 1, p1 = indptr[n1] >> 1;
  int ngroups = (p1 - p0) >> 2;
  for (int gi = qg; gi < ngroups; gi += 128) {
    int e = p0 + gi * 4;
    uint4 E0 = edges2[e], E1 = edges2[e + 1], E2 = edges2[e + 2], E3 = edges2[e + 3];
    uint4 v0 = H4[(size_t)(E0.x & SRCM) * 16 + ql];
    uint4 v1 = H4[(size_t)(E0.z & SRCM) * 16 + ql];
    uint4 v2 = H4[(size_t)(E1.x & SRCM) * 16 + ql];
    uint4 v3 = H4[(size_t)(E1.z & SRCM) * 16 + ql];
    uint4 v4 = H4[(size_t)(E2.x & SRCM) * 16 + ql];
    uint4 v5 = H4[(size_t)(E2.z & SRCM) * 16 + ql];
    uint4 v6 = H4[(size_t)(E3.x & SRCM) * 16 + ql];
    uint4 v7 = H4[(size_t)(E3.z & SRCM) * 16 + ql];
    float w0 = __uint_as_float(E0.y), w1 = __uint_as_float(E0.w);
    float w2 = __uint_as_float(E1.y), w3 = __uint_as_float(E1.w);
    float w4 = __uint_as_float(E2.y), w5 = __uint_as_float(E2.w);
    float w6 = __uint_as_float(E3.y), w7 = __uint_as_float(E3.w);
    a0 += w0 * bflo(v0.x); a1 += w0 * bfhi(v0.x); a2 += w0 * bflo(v0.y); a3 += w0 * bfhi(v0.y);
    a4 += w0 * bflo(v0.z); a5 += w0 * bfhi(v0.z); a6 += w0 * bflo(v0.w); a7 += w0 * bfhi(v0.w);
    a0 += w1 * bflo(v1.x); a1 += w1 * bfhi(v1.x); a2 += w1 * bflo(v1.y); a3 += w1 * bfhi(v1.y);
    a4 += w1 * bflo(v1.z); a5 += w1 * bfhi(v1.z); a6 += w1 * bflo(v1.w); a7 += w1 * bfhi(v1.w);
    a0 += w2 * bflo(v2.x); a1 += w2 * bfhi(v2.x); a2 += w2 * bflo(v2.y); a3 += w2 * bfhi(v2.y);
    a4 += w2 * bflo(v2.z); a5 += w2 * bfhi(v2.z); a6 += w2 * bflo(v2.w); a7 += w2 * bfhi(v2.w);
    a0 += w3 * bflo(v3.x); a1 += w3 * bfhi(v3.x); a2 += w3 * bflo(v3.y); a3 += w3 * bfhi(v3.y);
    a4 += w3 * bflo(v3.z); a5 += w3 * bfhi(v3.z); a6 += w3 * bflo(v3.w); a7 += w3 * bfhi(v3.w);
    a0 += w4 * bflo(v4.x); a1 += w4 * bfhi(v4.x); a2 += w4 * bflo(v4.y); a3 += w4 * bfhi(v4.y);
    a4 += w4 * bflo(v4.z); a5 += w4 * bfhi(v4.z); a6 += w4 * bflo(v4.w); a7 += w4 * bfhi(v4.w);
    a0 += w5 * bflo(v5.x); a1 += w5 * bfhi(v5.x); a2 += w5 * bflo(v5.y); a3 += w5 * bfhi(v5.y);
    a4 += w5 * bflo(v5.z); a5 += w5 * bfhi(v5.z); a6 += w5 * bflo(v5.w); a7 += w5 * bfhi(v5.w);
    a0 += w6 * bflo(v6.x); a1 += w6 * bfhi(v6.x); a2 += w6 * bflo(v6.y); a3 += w6 * bfhi(v6.y);
    a4 += w6 * bflo(v6.z); a5 += w6 * bfhi(v6.z); a6 += w6 * bflo(v6.w); a7 += w6 * bfhi(v6.w);
    a0 += w7 * bflo(v7.x); a1 += w7 * bfhi(v7.x); a2 += w7 * bflo(v7.y); a3 += w7 * bfhi(v7.y);
    a4 += w7 * bflo(v7.z); a5 += w7 * bfhi(v7.z); a6 += w7 * bflo(v7.w); a7 += w7 * bfhi(v7.w);
  }

  float* zq = &zred[q][ql * 8];
  zq[0] = a0; zq[1] = a1; zq[2] = a2; zq[3] = a3;
  zq[4] = a4; zq[5] = a5; zq[6] = a6; zq[7] = a7;
  __syncthreads();
  int t = threadIdx.x;
  if (t < FD) {
    float sum = 0.f;
#pragma unroll
    for (int qq = 0; qq < 16; ++qq) sum += zred[qq][t];
    Zpart[(size_t)(g * 8 + s) * FD + t] = sum;
  }
}

// ---------------- head3: one block per graph ----------------
__global__ void k_head3(const float* __restrict__ Zpart, const int* __restrict__ starts,
                        const int* __restrict__ ends, const float* __restrict__ w3wl,
                        const float* __restrict__ bl, float* __restrict__ out) {
  __shared__ float wpart[2][2];
  int g = blockIdx.x;
  int t = threadIdx.x;  // 128
  float zsum = 0.f;
#pragma unroll
  for (int s = 0; s < 8; ++s) zsum += Zpart[(size_t)(g * 8 + s) * FD + t];
  float a0 = zsum * w3wl[t * 2];
  float a1 = zsum * w3wl[t * 2 + 1];
#pragma unroll
  for (int d = 32; d; d >>= 1) {
    a0 += __shfl_down(a0, d);
    a1 += __shfl_down(a1, d);
  }
  int lane = t & 63, wv = t >> 6;
  if (lane == 0) { wpart[wv][0] = a0; wpart[wv][1] = a1; }
  __syncthreads();
  if (t == 0) {
    int cnt = ends[g] - starts[g];
    if (cnt < 0) cnt = 0;
    float inv = 1.f / (float)(cnt > 0 ? cnt : 1);
    float s0 = (wpart[0][0] + wpart[1][0]) * inv + (cnt > 0 ? w3wl[FD * 2] : 0.f) + bl[0];
    float s1 = (wpart[0][1] + wpart[1][1]) * inv + (cnt > 0 ? w3wl[FD * 2 + 1] : 0.f) + bl[1];
    out[g * 2] = s0;
    out[g * 2 + 1] = s1;
  }
}

// ---------------- host ----------------

extern "C" void kernel_launch(void* const* d_in, const int* in_sizes, int n_in,
                              void* d_out, int out_size, void* d_ws, size_t ws_size,
                              hipStream_t stream) {
  const float* x  = (const float*)d_in[0];
  const int* ei   = (const int*)d_in[1];
  const int* bat  = (const int*)d_in[2];
  const float* W1 = (const float*)d_in[3];
  const float* b1 = (const float*)d_in[4];
  const float* W2 = (const float*)d_in[5];
  const float* b2 = (const float*)d_in[6];
  const float* W3 = (const float*)d_in[7];
  const float* b3 = (const float*)d_in[8];
  const float* Wl = (const float*)d_in[9];
  const float* bl = (const float*)d_in[10];
  float* out = (float*)d_out;

  char* ws = (char*)d_ws;
  size_t off = 0;
  auto alloc = [&](size_t bytes) {
    void* p = ws + off;
    off += (bytes + 255) & ~(size_t)255;
    return p;
  };
  int* counts  = (int*)alloc(NN * 4);
  int* cursor  = (int*)alloc(NN * 4);
  int* indptr  = (int*)alloc((NN + 1) * 4);
  float* dinv  = (float*)alloc(NN * 4);
  int* bsum    = (int*)alloc(NB * 4);
  int* starts  = (int*)alloc(NG * 4);
  int* ends    = (int*)alloc(NG * 4);
  float* Zpart = (float*)alloc(NG * 8 * FD * 4);
  float* w3wl  = (float*)alloc((FD * 2 + 2) * 4);
  uint2* edges = (uint2*)alloc((size_t)EPAD * 8);
  unsigned short* Hb   = (unsigned short*)alloc((size_t)NN * FD * 2);
  unsigned short* Abuf = (unsigned short*)alloc((size_t)NN * FD * 2);
  unsigned short* WTh  = (unsigned short*)alloc(2 * FD * FD * 2);
  unsigned short* WTl  = (unsigned short*)alloc(2 * FD * FD * 2);

  const int* row = ei;
  const int* col = ei + NE;

  hipMemsetAsync(counts, 0, (size_t)((char*)cursor - (char*)counts) + NN * 4, stream);
  k_prep<<<(NE + 255) / 256, 256, 0, stream>>>(col, counts, W1, W2, W3, Wl, b3,
                                               WTh, WTl, w3wl, bat, starts, ends);
  k_bsum<<<NB, 1024, 0, stream>>>(counts, bsum, dinv);
  k_scan2<<<NB, 1024, 0, stream>>>(counts, bsum, indptr);
  k_fill<<<(NE + 255) / 256, 256, 0, stream>>>(row, col, indptr, cursor, counts,
                                               dinv, edges);

  int aggGrid = (NN + 15) / 16;

  k_gemm<1><<<GEMM_BLOCKS, 256, 0, stream>>>(x, WTh, WTl, Hb);
  k_agg<<<aggGrid, 256, 0, stream>>>((const uint4*)Hb, indptr, (const uint4*)edges, dinv, b1,
                                     (uint4*)Abuf, 1);
  k_gemm<0><<<GEMM_BLOCKS, 256, 0, stream>>>(Abuf, WTh + FD * FD, WTl + FD * FD, Hb);
  k_agg<<<aggGrid, 256, 0, stream>>>((const uint4*)Hb, indptr, (const uint4*)edges, dinv, b2,
                                     (uint4*)Abuf, 1);
  k_zacc<<<NG * 8, 256, 0, stream>>>((const uint4*)Abuf, (const uint4*)edges, indptr, dinv,
                                     starts, ends, Zpart);
  k_head3<<<NG, 128, 0, stream>>>(Zpart, starts, ends, w3wl, bl, out);
}